// Round 1
// baseline (229.619 us; speedup 1.0000x reference)
//
#include <hip/hip_runtime.h>

#define NPTS  16384
#define BATCH 16
#define PAD   17

__launch_bounds__(256, 3)
__global__ void conn_kernel(const float* __restrict__ inp,
                            const float* __restrict__ W1g,
                            const float* __restrict__ b1g,
                            const float* __restrict__ W2g,
                            const float* __restrict__ b2g,
                            float* __restrict__ out)
{
    __shared__ float S2[256][PAD];   // symmetrized W2: S2[p] = W2[p] + W2[pT]
    __shared__ float Js[256][PAD];   // per-point Jacobian J[p][l]
    __shared__ float W1s[16][PAD];
    __shared__ float b1s[16];
    __shared__ float bsym[256];
    __shared__ float xb[BATCH][16];
    __shared__ float vb[BATCH][16];
    __shared__ float hb[BATCH][16];
    __shared__ float tb[BATCH][16];
    __shared__ float Ab[BATCH][16];

    const int tid = threadIdx.x;

    // ---- setup: W1, b1 ----
    W1s[tid >> 4][tid & 15] = W1g[tid];
    if (tid < 16) b1s[tid] = b1g[tid];

    // stage W2 into Js (coalesced), then build S2, bsym
    #pragma unroll
    for (int q = 0; q < 16; ++q) {
        int f = q * 256 + tid;
        Js[f >> 4][f & 15] = W2g[f];
    }
    __syncthreads();
    {
        int p  = tid;                          // pair index i*16+j
        int pT = ((p & 15) << 4) | (p >> 4);   // j*16+i
        #pragma unroll
        for (int k = 0; k < 16; ++k)
            S2[p][k] = Js[p][k] + Js[pT][k];
        bsym[p] = b2g[p] + b2g[pT];
    }

    const int base = blockIdx.x * BATCH;

    // ---- stage inputs: 16 points x 32 floats ----
    #pragma unroll
    for (int it = 0; it < 2; ++it) {
        int idx = it * 256 + tid;
        float val = inp[base * 32 + idx];
        int pt = idx >> 5, c = idx & 31;
        if (c < 16) xb[pt][c] = val; else vb[pt][c - 16] = val;
    }
    __syncthreads();

    // ---- phase A: h, t for all 16 points (thread = (pt, k)) ----
    {
        int pt = tid >> 4, k = tid & 15;
        float pre = b1s[k];
        #pragma unroll
        for (int l = 0; l < 16; ++l) pre += W1s[k][l] * xb[pt][l];
        float h = tanhf(pre);
        hb[pt][k] = h;
        tb[pt][k] = 1.0f - h * h;
    }
    __syncthreads();

    const int l_of = tid >> 4;   // 0..15 across the block
    const int i_of = tid & 15;

    // ---- per point: J then A[l] ----
    for (int pt = 0; pt < BATCH; ++pt) {
        // phase B: thread p computes J[p][0..15] = sum_k S2[p][k]*t[k]*W1[k][:]
        {
            int p = tid;
            float c_[16];
            #pragma unroll
            for (int k = 0; k < 16; ++k) c_[k] = S2[p][k] * tb[pt][k];
            #pragma unroll
            for (int l = 0; l < 16; ++l) {
                float s = 0.f;
                #pragma unroll
                for (int k = 0; k < 16; ++k) s += c_[k] * W1s[k][l];
                Js[p][l] = s;
            }
        }
        __syncthreads();
        // phase C: A[l] = sum_{i,j} v_i v_j J[i,j,l]^2 J[l,i,j]; thread=(l,i)
        {
            float vi = vb[pt][i_of];
            float part = 0.f;
            #pragma unroll
            for (int j = 0; j < 16; ++j) {
                float a = Js[(i_of << 4) | j][l_of];   // J[i,j,l]
                float b = Js[(l_of << 4) | i_of][j];   // J[l,i,j]
                part += vb[pt][j] * a * a * b;
            }
            part *= vi;
            #pragma unroll
            for (int m = 1; m < 16; m <<= 1)
                part += __shfl_xor(part, m, 16);
            if (i_of == 0) Ab[pt][l_of] = part;
        }
        __syncthreads();
    }

    // ---- phase D: batched solve g y = A, dv = 0.5 y; thread = (pt, r) ----
    {
        int pt = tid >> 4, r = tid & 15;
        float grow[16];
        #pragma unroll
        for (int c = 0; c < 16; ++c) {
            float s = bsym[(r << 4) | c];
            #pragma unroll
            for (int k = 0; k < 16; ++k) s += S2[(r << 4) | c][k] * hb[pt][k];
            grow[c] = s;
        }
        float rhs = Ab[pt][r];
        bool done = false;
        int myvar = 0;
        #pragma unroll   // full unroll: keeps grow[]/pc[] statically indexed
        for (int s = 0; s < 16; ++s) {
            float cand = done ? -1.0f : fabsf(grow[s]);
            float bv = cand; int bi = r;
            #pragma unroll
            for (int m = 8; m >= 1; m >>= 1) {
                float ov = __shfl_xor(bv, m, 16);
                int oi = __shfl_xor(bi, m, 16);
                if (ov > bv || (ov == bv && oi < bi)) { bv = ov; bi = oi; }
            }
            float pc[16];
            #pragma unroll
            for (int c = 0; c < 16; ++c) pc[c] = __shfl(grow[c], bi, 16);
            float prhs = __shfl(rhs, bi, 16);
            float pv = pc[s];
            if (r == bi) {
                float invp = 1.0f / pv;
                #pragma unroll
                for (int c = 0; c < 16; ++c) grow[c] *= invp;
                rhs *= invp;
                done = true; myvar = s;
            } else {
                float f = grow[s] / pv;
                #pragma unroll
                for (int c = 0; c < 16; ++c) grow[c] -= f * pc[c];
                rhs -= f * prhs;
            }
        }
        int n = base + pt;
        out[n * 32 + r] = vb[pt][r];
        out[n * 32 + 16 + myvar] = 0.5f * rhs;
    }
}

extern "C" void kernel_launch(void* const* d_in, const int* in_sizes, int n_in,
                              void* d_out, int out_size, void* d_ws, size_t ws_size,
                              hipStream_t stream) {
    const float* inp = (const float*)d_in[1];
    const float* W1  = (const float*)d_in[2];
    const float* b1  = (const float*)d_in[3];
    const float* W2  = (const float*)d_in[4];
    const float* b2  = (const float*)d_in[5];
    float* outp = (float*)d_out;
    dim3 grid(NPTS / BATCH);   // 1024 blocks x 256 threads, 16 points each
    conn_kernel<<<grid, 256, 0, stream>>>(inp, W1, b1, W2, b2, outp);
}

// Round 2
// 121.897 us; speedup vs baseline: 1.8837x; 1.8837x over previous
//
#include <hip/hip_runtime.h>

#define NPTS  16384
#define BATCH 16

// LDS float offsets
#define OFF_W1   0       // W1 [16][20]  (row k at OFF_W1 + 20k, 16B-aligned)
#define OFF_B1   320     // b1 [16]
#define OFF_VB   336     // v  [16][16]
#define OFF_HB   592     // h  [16][16]
#define OFF_TB   848     // t  [16][16]
#define OFF_XA   1104    // x  [16][16] in phase A; reused as Ab[16][16] afterwards
#define OFF_U    1360    // P0 (4352) + P1 (4352); later g_all[pt*320 + r*20 + c]
#define P_STRIDE 4352
#define LDS_FLOATS (OFF_U + 2 * P_STRIDE)   // 10064 floats = 40256 B

__launch_bounds__(256, 3)
__global__ void conn_kernel(const float* __restrict__ inp,
                            const float* __restrict__ W1g,
                            const float* __restrict__ b1g,
                            const float* __restrict__ W2g,
                            const float* __restrict__ b2g,
                            float* __restrict__ out)
{
    __shared__ float SH[LDS_FLOATS];
    const int tid  = threadIdx.x;
    const int i_of = tid >> 4;    // 0..15
    const int j_of = tid & 15;

    // ---- per-thread constants: S2 row (registers!) and symmetrized b2 ----
    const int pT = (j_of << 4) | i_of;
    float s2[16];
    {
        const float4* wa = reinterpret_cast<const float4*>(W2g + tid * 16);
        const float4* wb = reinterpret_cast<const float4*>(W2g + pT  * 16);
        #pragma unroll
        for (int q = 0; q < 4; ++q) {
            float4 A = wa[q], B = wb[q];
            s2[4*q+0] = A.x + B.x;
            s2[4*q+1] = A.y + B.y;
            s2[4*q+2] = A.z + B.z;
            s2[4*q+3] = A.w + B.w;
        }
    }
    const float breg = b2g[tid] + b2g[pT];

    // ---- stage W1 (layout [k][20]) , b1, inputs ----
    SH[OFF_W1 + i_of * 20 + j_of] = W1g[tid];
    if (tid < 16) SH[OFF_B1 + tid] = b1g[tid];

    const int base = blockIdx.x * BATCH;
    if (tid < 128) {
        float4 vle = reinterpret_cast<const float4*>(inp + base * 32)[tid];
        int idx = tid * 4, pt = idx >> 5, c = idx & 31;
        float* dst = (c < 16) ? &SH[OFF_XA + pt * 16 + c]
                              : &SH[OFF_VB + pt * 16 + (c - 16)];
        dst[0] = vle.x; dst[1] = vle.y; dst[2] = vle.z; dst[3] = vle.w;
    }
    __syncthreads();

    // ---- phase A: h, t  (thread = (pt=i_of, k=j_of)) ----
    {
        const int pt = i_of, k = j_of;
        const float4* wrow = reinterpret_cast<const float4*>(&SH[OFF_W1 + k * 20]);
        const float4* xrow = reinterpret_cast<const float4*>(&SH[OFF_XA + pt * 16]);
        float pre = SH[OFF_B1 + k];
        #pragma unroll
        for (int q = 0; q < 4; ++q) {
            float4 w = wrow[q], x = xrow[q];
            pre += w.x * x.x + w.y * x.y + w.z * x.z + w.w * x.w;
        }
        float h = tanhf(pre);
        SH[OFF_HB + pt * 16 + k] = h;
        SH[OFF_TB + pt * 16 + k] = 1.0f - h * h;
    }
    __syncthreads();

    float* const P0 = &SH[OFF_U];
    float* const P1 = &SH[OFF_U + P_STRIDE];

    // ---- main loop: 8 chunks of 2 points ----
    #pragma unroll 1
    for (int ch = 0; ch < 8; ++ch) {
        const int ptA = 2 * ch, ptB = 2 * ch + 1;

        float cA[16], cB[16], jA[16], jB[16];
        {
            const float4* tA4 = reinterpret_cast<const float4*>(&SH[OFF_TB + ptA * 16]);
            const float4* tB4 = reinterpret_cast<const float4*>(&SH[OFF_TB + ptB * 16]);
            #pragma unroll
            for (int q = 0; q < 4; ++q) {
                float4 ta = tA4[q], tb = tB4[q];
                cA[4*q+0] = s2[4*q+0] * ta.x;  cB[4*q+0] = s2[4*q+0] * tb.x;
                cA[4*q+1] = s2[4*q+1] * ta.y;  cB[4*q+1] = s2[4*q+1] * tb.y;
                cA[4*q+2] = s2[4*q+2] * ta.z;  cB[4*q+2] = s2[4*q+2] * tb.z;
                cA[4*q+3] = s2[4*q+3] * ta.w;  cB[4*q+3] = s2[4*q+3] * tb.w;
            }
        }
        #pragma unroll
        for (int l = 0; l < 16; ++l) { jA[l] = 0.f; jB[l] = 0.f; }

        // J[p][l] = sum_k c[k] * W1[k][l]  — W1 rows broadcast from LDS
        #pragma unroll
        for (int k = 0; k < 16; ++k) {
            const float4* w4 = reinterpret_cast<const float4*>(&SH[OFF_W1 + k * 20]);
            float4 w0 = w4[0], w1 = w4[1], w2 = w4[2], w3 = w4[3];
            float ca = cA[k], cb = cB[k];
            jA[0]  += ca * w0.x; jA[1]  += ca * w0.y; jA[2]  += ca * w0.z; jA[3]  += ca * w0.w;
            jA[4]  += ca * w1.x; jA[5]  += ca * w1.y; jA[6]  += ca * w1.z; jA[7]  += ca * w1.w;
            jA[8]  += ca * w2.x; jA[9]  += ca * w2.y; jA[10] += ca * w2.z; jA[11] += ca * w2.w;
            jA[12] += ca * w3.x; jA[13] += ca * w3.y; jA[14] += ca * w3.z; jA[15] += ca * w3.w;
            jB[0]  += cb * w0.x; jB[1]  += cb * w0.y; jB[2]  += cb * w0.z; jB[3]  += cb * w0.w;
            jB[4]  += cb * w1.x; jB[5]  += cb * w1.y; jB[6]  += cb * w1.z; jB[7]  += cb * w1.w;
            jB[8]  += cb * w2.x; jB[9]  += cb * w2.y; jB[10] += cb * w2.z; jB[11] += cb * w2.w;
            jB[12] += cb * w3.x; jB[13] += cb * w3.y; jB[14] += cb * w3.z; jB[15] += cb * w3.w;
        }

        // P[i,j,l] = v_i v_j J[i,j,l]^2  at addr l*272 + j*17 + i  (reads conflict-free)
        {
            float pfA = SH[OFF_VB + ptA * 16 + i_of] * SH[OFF_VB + ptA * 16 + j_of];
            float pfB = SH[OFF_VB + ptB * 16 + i_of] * SH[OFF_VB + ptB * 16 + j_of];
            #pragma unroll
            for (int l = 0; l < 16; ++l) {
                P0[l * 272 + j_of * 17 + i_of] = pfA * jA[l] * jA[l];
                P1[l * 272 + j_of * 17 + i_of] = pfB * jB[l] * jB[l];
            }
        }
        __syncthreads();

        // phase C: thread (a=i_of, b=j_of): s = sum_j J[a,b,j] * P[b,j,a]
        {
            float sA = 0.f, sB = 0.f;
            #pragma unroll
            for (int j = 0; j < 16; ++j) {
                sA += jA[j] * P0[i_of * 272 + j * 17 + j_of];
                sB += jB[j] * P1[i_of * 272 + j * 17 + j_of];
            }
            #pragma unroll
            for (int m = 1; m < 16; m <<= 1) {
                sA += __shfl_xor(sA, m, 16);
                sB += __shfl_xor(sB, m, 16);
            }
            if (j_of == 0) {
                SH[OFF_XA + ptA * 16 + i_of] = sA;   // Ab[ptA][a]
                SH[OFF_XA + ptB * 16 + i_of] = sB;
            }
        }
        __syncthreads();
    }

    // ---- g formation: g[p]_pt = sum_k s2[k] h_pt[k] + breg ; transpose via LDS ----
    {
        float greg[16];
        #pragma unroll
        for (int pt = 0; pt < 16; ++pt) {
            const float4* h4 = reinterpret_cast<const float4*>(&SH[OFF_HB + pt * 16]);
            float g = breg;
            #pragma unroll
            for (int q = 0; q < 4; ++q) {
                float4 h = h4[q];
                g += s2[4*q+0] * h.x + s2[4*q+1] * h.y + s2[4*q+2] * h.z + s2[4*q+3] * h.w;
            }
            greg[pt] = g;
        }
        #pragma unroll
        for (int pt = 0; pt < 16; ++pt)
            SH[OFF_U + pt * 320 + i_of * 20 + j_of] = greg[pt];
    }
    __syncthreads();

    // ---- phase D: solve g y = A, dv = 0.5 y  (thread = (pt=i_of, r=j_of)) ----
    {
        const int pt = i_of, r = j_of;
        float grow[16];
        const float4* g4 = reinterpret_cast<const float4*>(&SH[OFF_U + pt * 320 + r * 20]);
        #pragma unroll
        for (int q = 0; q < 4; ++q) {
            float4 G = g4[q];
            grow[4*q+0] = G.x; grow[4*q+1] = G.y; grow[4*q+2] = G.z; grow[4*q+3] = G.w;
        }
        float rhs = SH[OFF_XA + pt * 16 + r];

        bool done = false; int myvar = 0;
        #pragma unroll
        for (int s = 0; s < 16; ++s) {
            float cand = done ? -1.0f : fabsf(grow[s]);
            float bv = cand; int bi = r;
            #pragma unroll
            for (int m = 8; m >= 1; m >>= 1) {
                float ov = __shfl_xor(bv, m, 16);
                int   oi = __shfl_xor(bi, m, 16);
                if (ov > bv || (ov == bv && oi < bi)) { bv = ov; bi = oi; }
            }
            float pv   = __shfl(grow[s], bi, 16);
            float prhs = __shfl(rhs,     bi, 16);
            float invp = 1.0f / pv;
            bool  isP  = (r == bi);
            float f    = grow[s] * invp;
            #pragma unroll
            for (int c = 0; c < 16; ++c) {
                float pc  = __shfl(grow[c], bi, 16);   // all lanes execute (no divergence)
                float upd = grow[c] - f * pc;
                float piv = grow[c] * invp;
                grow[c] = isP ? piv : upd;
            }
            float updr = rhs - f * prhs;
            float pivr = rhs * invp;
            rhs = isP ? pivr : updr;
            if (isP) { done = true; myvar = s; }
        }

        const int n = base + pt;
        out[n * 32 + r]           = SH[OFF_VB + pt * 16 + r];
        out[n * 32 + 16 + myvar]  = 0.5f * rhs;
    }
}

extern "C" void kernel_launch(void* const* d_in, const int* in_sizes, int n_in,
                              void* d_out, int out_size, void* d_ws, size_t ws_size,
                              hipStream_t stream) {
    const float* inp = (const float*)d_in[1];
    const float* W1  = (const float*)d_in[2];
    const float* b1  = (const float*)d_in[3];
    const float* W2  = (const float*)d_in[4];
    const float* b2  = (const float*)d_in[5];
    float* outp = (float*)d_out;
    conn_kernel<<<dim3(NPTS / BATCH), 256, 0, stream>>>(inp, W1, b1, W2, b2, outp);
}